// Round 3
// baseline (161.050 us; speedup 1.0000x reference)
//
#include <hip/hip_runtime.h>
#include <hip/hip_bf16.h>

#define DD 512
// ws layout (bytes)
#define OFF_K   0        // k fp32 [4][512]
#define OFF_V   8192     // v fp32 [4][512]
#define OFF_C   16384    // c fp32 [4]
#define OFF_VB  16448    // Vb fp32 [4][64]
#define OFF_W1F 18432    // W1 top fragments bf16, 65536 B
#define OFF_KQF 83968    // Kq fragments bf16, 16384 B (contiguous with W1F)

typedef __attribute__((ext_vector_type(8))) __bf16 bf16x8;
typedef __attribute__((ext_vector_type(4))) float f32x4;
typedef unsigned short u16;

__device__ __forceinline__ u16 f2bf(float f) {
  unsigned u = __builtin_bit_cast(unsigned, f);
  u += 0x7fffu + ((u >> 16) & 1u);   // RNE
  return (u16)(u >> 16);
}

// ---- prep 1: k = prim@Wk+bk, v = prim@Wv+bv (fp32 in, fp32 out) ----
__global__ void prep_kv(const float* __restrict__ emb, const int* __restrict__ seq,
                        const float* __restrict__ Wk, const float* __restrict__ bk,
                        const float* __restrict__ Wv, const float* __restrict__ bv,
                        float* __restrict__ ws_kv) {
  int t = blockIdx.x * 256 + threadIdx.x;          // [0, 4096)
  int kind = t >> 11, p = (t >> 9) & 3, d = t & 511;
  const float* W = kind ? Wv : Wk;
  const float* b = kind ? bv : bk;
  const float* pr = emb + seq[p] * DD;
  float a0 = 0.f, a1 = 0.f, a2 = 0.f, a3 = 0.f;
  for (int j = 0; j < DD; j += 4) {
    a0 += pr[j]     * W[j * DD + d];
    a1 += pr[j + 1] * W[(j + 1) * DD + d];
    a2 += pr[j + 2] * W[(j + 2) * DD + d];
    a3 += pr[j + 3] * W[(j + 3) * DD + d];
  }
  ws_kv[kind * 2048 + p * 512 + d] = ((a0 + a1) + (a2 + a3)) + b[d];
}

// ---- prep 2: Kq fragments (bf16), W1_top fragments (bf16), Vb, c ----
__global__ void prep_frag(const float* __restrict__ Wq, const float* __restrict__ bq,
                          const float* __restrict__ W1, char* __restrict__ ws) {
  const float* kk = (const float*)(ws + OFF_K);
  const float* vv = (const float*)(ws + OFF_V);
  int t = blockIdx.x * 256 + threadIdx.x;
  if (t < 8192) {                       // Kqfrag[kt][l][j], zero-padded p>=4
    int kt = t >> 9, l = (t >> 3) & 63, j = t & 7;
    int p = l & 15;
    u16 val = 0;
    if (p < 4) {
      int dg = kt * 32 + ((l >> 4) << 3) + j;      // x-feature index
      const float* wq = Wq + dg * DD;              // row dg of Wq (in,out)
      const float* kp = kk + p * DD;
      float a0 = 0.f, a1 = 0.f, a2 = 0.f, a3 = 0.f;
      for (int u = 0; u < DD; u += 4) {
        a0 += wq[u]     * kp[u];
        a1 += wq[u + 1] * kp[u + 1];
        a2 += wq[u + 2] * kp[u + 2];
        a3 += wq[u + 3] * kp[u + 3];
      }
      val = f2bf((a0 + a1) + (a2 + a3));
    }
    *(u16*)(ws + OFF_KQF + t * 2) = val;
  } else if (t < 12288) {               // W1frag[kt][ct][l][0..7]
    int u = t - 8192;
    int kt = u >> 8, ct = (u >> 6) & 3, l = u & 63;
    int kb = kt * 32 + ((l >> 4) << 3);
    int col = ct * 16 + (l & 15);
    u16* dst = (u16*)(ws + OFF_W1F + u * 16);
    #pragma unroll
    for (int j = 0; j < 8; ++j) dst[j] = f2bf(W1[(kb + j) * 64 + col]);
  } else if (t < 12544) {               // Vb[p][col] = v[p] . W1_bot[:,col]
    int u = t - 12288;
    int p = u >> 6, col = u & 63;
    float acc = 0.f;
    for (int d = 0; d < DD; ++d) acc += vv[p * 512 + d] * W1[(512 + d) * 64 + col];
    ((float*)(ws + OFF_VB))[p * 64 + col] = acc;
  } else if (t < 12548) {               // c[p] = bq . k[p]
    int p = t - 12544;
    float acc = 0.f;
    for (int d = 0; d < DD; ++d) acc += bq[d] * kk[p * 512 + d];
    ((float*)(ws + OFF_C))[p] = acc;
  }
}

// ---- main: 512 persistent blocks x 256 thr; 8 x 64-row tiles per block ----
__launch_bounds__(256, 2)
__global__ void credit_main(const float* __restrict__ x, const char* __restrict__ ws,
                            const float* __restrict__ b1, const float* __restrict__ W2,
                            const float* __restrict__ b2, float* __restrict__ out) {
  __shared__ char lds[81920];            // W1frag 64K + Kqfrag 16K
  {
    const uint4* src = (const uint4*)(ws + OFF_W1F);
    uint4* dst = (uint4*)lds;
    for (int i = threadIdx.x; i < 5120; i += 256) dst[i] = src[i];
  }
  const int l = threadIdx.x & 63;
  const int wv = threadIdx.x >> 6;
  const int q = l & 15;                  // A row / D col / p index
  const int g = l >> 4;                  // k-group

  float cv = 0.f;
  if (q < 4) cv = ((const float*)(ws + OFF_C))[q];
  float vb[4][4], b1v[4], w2v[4];
  const float* vbf = (const float*)(ws + OFF_VB);
  #pragma unroll
  for (int p = 0; p < 4; ++p)
    #pragma unroll
    for (int ct = 0; ct < 4; ++ct) vb[p][ct] = vbf[p * 64 + ct * 16 + q];
  #pragma unroll
  for (int ct = 0; ct < 4; ++ct) { b1v[ct] = b1[ct * 16 + q]; w2v[ct] = W2[ct * 16 + q]; }
  const float b2v = b2[0];
  __syncthreads();

  for (int it = 0; it < 8; ++it) {
    const int rowbase = (blockIdx.x * 8 + it) * 64 + wv * 16;
    const float* xr = x + (size_t)(rowbase + q) * DD + g * 8;
    f32x4 zero = {0.f, 0.f, 0.f, 0.f};
    f32x4 acc[4];
    #pragma unroll
    for (int ct = 0; ct < 4; ++ct) acc[ct] = zero;
    f32x4 sacc = zero;

    #pragma unroll 4
    for (int kt = 0; kt < 16; ++kt) {
      const float4 a0 = *(const float4*)(xr + kt * 32);
      const float4 a1 = *(const float4*)(xr + kt * 32 + 4);
      uint4 pk;
      pk.x = (unsigned)f2bf(a0.x) | ((unsigned)f2bf(a0.y) << 16);
      pk.y = (unsigned)f2bf(a0.z) | ((unsigned)f2bf(a0.w) << 16);
      pk.z = (unsigned)f2bf(a1.x) | ((unsigned)f2bf(a1.y) << 16);
      pk.w = (unsigned)f2bf(a1.z) | ((unsigned)f2bf(a1.w) << 16);
      const bf16x8 af = __builtin_bit_cast(bf16x8, pk);
      const char* wbase = lds + (size_t)(kt * 4 * 64 + l) * 16;
      #pragma unroll
      for (int ct = 0; ct < 4; ++ct)
        acc[ct] = __builtin_amdgcn_mfma_f32_16x16x32_bf16(
            af, *(const bf16x8*)(wbase + ct * 1024), acc[ct], 0, 0, 0);
      const bf16x8 kqf = *(const bf16x8*)(lds + 65536 + (size_t)(kt * 64 + l) * 16);
      sacc = __builtin_amdgcn_mfma_f32_16x16x32_bf16(af, kqf, sacc, 0, 0, 0);
    }

    // softmax over p (lanes q=0..3 of each 16-lane group hold p=q)
    const float rs = 0.04419417382415922f;   // 1/sqrt(512)
    float attn[4];
    #pragma unroll
    for (int r = 0; r < 4; ++r) {
      float s = (sacc[r] + cv) * rs;
      float m = fmaxf(s, __shfl_xor(s, 1, 64));
      m = fmaxf(m, __shfl_xor(m, 2, 64));
      float e = __expf(s - m);
      float sm = e + __shfl_xor(e, 1, 64);
      sm += __shfl_xor(sm, 2, 64);
      attn[r] = e / sm;
    }
    if (q < 4) {
      #pragma unroll
      for (int r = 0; r < 4; ++r)
        out[262144 + (rowbase + g * 4 + r) * 4 + q] = attn[r];
    }
    // broadcast attn[p] of each row to all lanes
    float ap[4][4];
    #pragma unroll
    for (int p = 0; p < 4; ++p) {
      const int src = (l & 48) + p;
      #pragma unroll
      for (int r = 0; r < 4; ++r) ap[p][r] = __shfl(attn[r], src, 64);
    }
    // h = relu(acc + b1 + attn@Vb); credit partial = h . W2
    float cred[4] = {0.f, 0.f, 0.f, 0.f};
    #pragma unroll
    for (int ct = 0; ct < 4; ++ct) {
      #pragma unroll
      for (int r = 0; r < 4; ++r) {
        float h = acc[ct][r] + b1v[ct];
        #pragma unroll
        for (int p = 0; p < 4; ++p) h += ap[p][r] * vb[p][ct];
        h = fmaxf(h, 0.f);
        cred[r] += h * w2v[ct];
      }
    }
    #pragma unroll
    for (int r = 0; r < 4; ++r) {
      float cz = cred[r];
      cz += __shfl_xor(cz, 1, 64);
      cz += __shfl_xor(cz, 2, 64);
      cz += __shfl_xor(cz, 4, 64);
      cz += __shfl_xor(cz, 8, 64);
      cred[r] = 1.f / (1.f + __expf(-(cz + b2v)));
    }
    if (q == 0) {
      float4 c4 = make_float4(cred[0], cred[1], cred[2], cred[3]);
      *(float4*)(out + rowbase + g * 4) = c4;
    }
  }
}

extern "C" void kernel_launch(void* const* d_in, const int* in_sizes, int n_in,
                              void* d_out, int out_size, void* d_ws, size_t ws_size,
                              hipStream_t stream) {
  const float* x   = (const float*)d_in[0];
  const int*   seq = (const int*)d_in[1];
  const float* emb = (const float*)d_in[2];
  const float* Wq  = (const float*)d_in[3];
  const float* bq  = (const float*)d_in[4];
  const float* Wk  = (const float*)d_in[5];
  const float* bk  = (const float*)d_in[6];
  const float* Wv  = (const float*)d_in[7];
  const float* bv  = (const float*)d_in[8];
  const float* W1  = (const float*)d_in[9];
  const float* b1  = (const float*)d_in[10];
  const float* W2  = (const float*)d_in[11];
  const float* b2  = (const float*)d_in[12];
  char* ws = (char*)d_ws;

  prep_kv<<<16, 256, 0, stream>>>(emb, seq, Wk, bk, Wv, bv, (float*)ws);
  prep_frag<<<50, 256, 0, stream>>>(Wq, bq, W1, ws);
  credit_main<<<512, 256, 0, stream>>>(x, ws, b1, W2, b2, (float*)d_out);
}

// Round 4
// 112.357 us; speedup vs baseline: 1.4334x; 1.4334x over previous
//
#include <hip/hip_runtime.h>
#include <hip/hip_bf16.h>

#define DD 512
// ws layout (bytes)
#define OFF_K   0        // k fp32 [4][512]
#define OFF_V   8192     // v fp32 [4][512]
#define OFF_C   16384    // c fp32 [4]
#define OFF_VB  16448    // Vb fp32 [4][64]
#define OFF_KQ  17472    // Kq fp32 [512][4]  (dg-major)
#define OFF_W1F 25664    // W1 top fragments bf16, 65536 B

typedef __attribute__((ext_vector_type(8))) __bf16 bf16x8;
typedef __attribute__((ext_vector_type(8))) float f32x8;
typedef __attribute__((ext_vector_type(4))) float f32x4;
typedef unsigned short u16;

__device__ __forceinline__ u16 f2bf(float f) {
  unsigned u = __builtin_bit_cast(unsigned, f);
  u += 0x7fffu + ((u >> 16) & 1u);   // RNE
  return (u16)(u >> 16);
}

// ---- prep1: k = prim@Wk+bk, v = prim@Wv+bv ----
// grid 64 x 512thr: block = (kind, p, dchunk); threads = 64 d x 8 jgroups
__global__ void prep_kv(const float* __restrict__ emb, const int* __restrict__ seq,
                        const float* __restrict__ Wk, const float* __restrict__ bk,
                        const float* __restrict__ Wv, const float* __restrict__ bv,
                        float* __restrict__ ws_kv) {
  __shared__ float red[8][64];
  const int b = blockIdx.x;
  const int kind = b >> 5, p = (b >> 3) & 3, dc = b & 7;
  const int dl = threadIdx.x & 63, jg = threadIdx.x >> 6;
  const int d = dc * 64 + dl;
  const float* W = kind ? Wv : Wk;
  const float* bias = kind ? bv : bk;
  const float* pr = emb + seq[p] * DD + jg * 64;
  const float* Wp = W + (size_t)(jg * 64) * DD + d;
  float a0 = 0.f, a1 = 0.f, a2 = 0.f, a3 = 0.f;
  #pragma unroll 4
  for (int j = 0; j < 64; j += 4) {
    a0 += pr[j]     * Wp[(size_t)j * DD];
    a1 += pr[j + 1] * Wp[(size_t)(j + 1) * DD];
    a2 += pr[j + 2] * Wp[(size_t)(j + 2) * DD];
    a3 += pr[j + 3] * Wp[(size_t)(j + 3) * DD];
  }
  red[jg][dl] = (a0 + a1) + (a2 + a3);
  __syncthreads();
  if (jg == 0) {
    float s = red[0][dl];
    #pragma unroll
    for (int g = 1; g < 8; ++g) s += red[g][dl];
    ws_kv[kind * 2048 + p * 512 + d] = s + bias[d];
  }
}

// ---- prep2: Kq dots, Vb, c, W1frag — wave-parallel ----
// grid 209 x 256thr
__global__ void prep_frag(const float* __restrict__ Wq, const float* __restrict__ bq,
                          const float* __restrict__ W1, char* __restrict__ ws) {
  const float* kk = (const float*)(ws + OFF_K);
  const float* vv = (const float*)(ws + OFF_V);
  const int b = blockIdx.x;
  const int lane = threadIdx.x & 63;
  const int wv = threadIdx.x >> 6;

  if (b < 128) {                       // Kq[dg][p] = Wq_row(dg) . k[p]
    const int dg = b * 4 + wv;
    const f32x8 wqv = *(const f32x8*)(Wq + (size_t)dg * DD + lane * 8);
    float a[4];
    #pragma unroll
    for (int p = 0; p < 4; ++p) {
      const f32x8 kv = *(const f32x8*)(kk + p * 512 + lane * 8);
      float s = 0.f;
      #pragma unroll
      for (int j = 0; j < 8; ++j) s += wqv[j] * kv[j];
      #pragma unroll
      for (int sft = 1; sft < 64; sft <<= 1) s += __shfl_xor(s, sft, 64);
      a[p] = s;
    }
    if (lane < 4) {
      float v = lane == 0 ? a[0] : lane == 1 ? a[1] : lane == 2 ? a[2] : a[3];
      ((float*)(ws + OFF_KQ))[dg * 4 + lane] = v;
    }
  } else if (b < 192) {                // Vb[p][col] = v[p] . W1_bot[:,col]
    const int idx = (b - 128) * 4 + wv;
    const int p = idx >> 6, col = idx & 63;
    const f32x8 vvv = *(const f32x8*)(vv + p * 512 + lane * 8);
    float s = 0.f;
    #pragma unroll
    for (int j = 0; j < 8; ++j) s += vvv[j] * W1[(size_t)(512 + lane * 8 + j) * 64 + col];
    #pragma unroll
    for (int sft = 1; sft < 64; sft <<= 1) s += __shfl_xor(s, sft, 64);
    if (lane == 0) ((float*)(ws + OFF_VB))[p * 64 + col] = s;
  } else if (b == 192) {               // c[p] = bq . k[p]
    if (wv < 4) {
      const f32x8 bqv = *(const f32x8*)(bq + lane * 8);
      const f32x8 kv = *(const f32x8*)(kk + wv * 512 + lane * 8);
      float s = 0.f;
      #pragma unroll
      for (int j = 0; j < 8; ++j) s += bqv[j] * kv[j];
      #pragma unroll
      for (int sft = 1; sft < 64; sft <<= 1) s += __shfl_xor(s, sft, 64);
      if (lane == 0) ((float*)(ws + OFF_C))[wv] = s;
    }
  } else {                             // W1frag[kt][ct][l][0..7] bf16
    const int u = (b - 193) * 256 + threadIdx.x;   // [0, 4096)
    const int kt = u >> 8, ct = (u >> 6) & 3, l = u & 63;
    const int kb = kt * 32 + ((l >> 4) << 3);
    const int col = ct * 16 + (l & 15);
    u16 buf[8];
    #pragma unroll
    for (int j = 0; j < 8; ++j) buf[j] = f2bf(W1[(size_t)(kb + j) * 64 + col]);
    *(uint4*)(ws + OFF_W1F + (size_t)u * 16) = *(const uint4*)buf;
  }
}

// ---- main: 512 blocks x 512 thr (8 waves); 2 blocks/CU; 4 x 128-row tiles ----
__launch_bounds__(512, 4)
__global__ void credit_main(const float* __restrict__ x, const char* __restrict__ ws,
                            const float* __restrict__ b1, const float* __restrict__ W2,
                            const float* __restrict__ b2, float* __restrict__ out) {
  __shared__ char lds[81920];            // W1frag 64K + Kqfrag 16K
  {
    const uint4* src = (const uint4*)(ws + OFF_W1F);
    uint4* dst = (uint4*)lds;
    #pragma unroll
    for (int i = 0; i < 8; ++i) dst[threadIdx.x + i * 512] = src[threadIdx.x + i * 512];
    // build Kqfrag bf16 from plain Kq fp32 (8KB, L2-resident)
    const float* kq = (const float*)(ws + OFF_KQ);
    const int e0 = threadIdx.x * 16;     // 16 u16 elements per thread
    const int kt = e0 >> 9;
    u16 buf[16];
    #pragma unroll
    for (int m = 0; m < 16; ++m) {
      const int e = e0 + m, l = (e >> 3) & 63, j = e & 7, p = l & 15;
      float v = 0.f;
      if (p < 4) v = kq[(kt * 32 + ((l >> 4) << 3) + j) * 4 + p];
      buf[m] = f2bf(v);
    }
    *(uint4*)(lds + 65536 + e0 * 2) = *(const uint4*)buf;
    *(uint4*)(lds + 65536 + e0 * 2 + 16) = *(const uint4*)(buf + 8);
  }
  const int l = threadIdx.x & 63;
  const int wv = threadIdx.x >> 6;       // 0..7
  const int q = l & 15;                  // A row / D col / p index
  const int g = l >> 4;                  // k-group

  float cv = 0.f;
  if (q < 4) cv = ((const float*)(ws + OFF_C))[q];
  float vb[4][4], b1v[4], w2v[4];
  const float* vbf = (const float*)(ws + OFF_VB);
  #pragma unroll
  for (int p = 0; p < 4; ++p)
    #pragma unroll
    for (int ct = 0; ct < 4; ++ct) vb[p][ct] = vbf[p * 64 + ct * 16 + q];
  #pragma unroll
  for (int ct = 0; ct < 4; ++ct) { b1v[ct] = b1[ct * 16 + q]; w2v[ct] = W2[ct * 16 + q]; }
  const float b2v = b2[0];
  __syncthreads();

  for (int it = 0; it < 4; ++it) {
    const int rowbase = (blockIdx.x * 4 + it) * 128 + wv * 16;
    const float* xr = x + (size_t)(rowbase + q) * DD + g * 8;
    f32x4 zero = {0.f, 0.f, 0.f, 0.f};
    f32x4 acc[4];
    #pragma unroll
    for (int ct = 0; ct < 4; ++ct) acc[ct] = zero;
    f32x4 sacc = zero;

    #pragma unroll 4
    for (int kt = 0; kt < 16; ++kt) {
      const f32x8 a = *(const f32x8*)(xr + kt * 32);
      const bf16x8 af = __builtin_convertvector(a, bf16x8);
      const char* wbase = lds + (size_t)(kt * 4 * 64 + l) * 16;
      #pragma unroll
      for (int ct = 0; ct < 4; ++ct)
        acc[ct] = __builtin_amdgcn_mfma_f32_16x16x32_bf16(
            af, *(const bf16x8*)(wbase + ct * 1024), acc[ct], 0, 0, 0);
      const bf16x8 kqf = *(const bf16x8*)(lds + 65536 + (size_t)(kt * 64 + l) * 16);
      sacc = __builtin_amdgcn_mfma_f32_16x16x32_bf16(af, kqf, sacc, 0, 0, 0);
    }

    // softmax over p (lanes q=0..3 of each 16-lane group hold p=q)
    const float rs = 0.04419417382415922f;   // 1/sqrt(512)
    float attn[4];
    #pragma unroll
    for (int r = 0; r < 4; ++r) {
      float s = (sacc[r] + cv) * rs;
      float m = fmaxf(s, __shfl_xor(s, 1, 64));
      m = fmaxf(m, __shfl_xor(m, 2, 64));
      float e = __expf(s - m);
      float sm = e + __shfl_xor(e, 1, 64);
      sm += __shfl_xor(sm, 2, 64);
      attn[r] = e / sm;
    }
    if (q < 4) {
      #pragma unroll
      for (int r = 0; r < 4; ++r)
        out[262144 + (rowbase + g * 4 + r) * 4 + q] = attn[r];
    }
    // broadcast attn[p] of each row to all lanes
    float ap[4][4];
    #pragma unroll
    for (int p = 0; p < 4; ++p) {
      const int src = (l & 48) + p;
      #pragma unroll
      for (int r = 0; r < 4; ++r) ap[p][r] = __shfl(attn[r], src, 64);
    }
    // h = relu(acc + b1 + attn@Vb); credit partial = h . W2
    float cred[4] = {0.f, 0.f, 0.f, 0.f};
    #pragma unroll
    for (int ct = 0; ct < 4; ++ct) {
      #pragma unroll
      for (int r = 0; r < 4; ++r) {
        float h = acc[ct][r] + b1v[ct];
        #pragma unroll
        for (int p = 0; p < 4; ++p) h += ap[p][r] * vb[p][ct];
        h = fmaxf(h, 0.f);
        cred[r] += h * w2v[ct];
      }
    }
    #pragma unroll
    for (int r = 0; r < 4; ++r) {
      float cz = cred[r];
      cz += __shfl_xor(cz, 1, 64);
      cz += __shfl_xor(cz, 2, 64);
      cz += __shfl_xor(cz, 4, 64);
      cz += __shfl_xor(cz, 8, 64);
      cred[r] = 1.f / (1.f + __expf(-(cz + b2v)));
    }
    if (q == 0) {
      float4 c4 = make_float4(cred[0], cred[1], cred[2], cred[3]);
      *(float4*)(out + rowbase + g * 4) = c4;
    }
  }
}

extern "C" void kernel_launch(void* const* d_in, const int* in_sizes, int n_in,
                              void* d_out, int out_size, void* d_ws, size_t ws_size,
                              hipStream_t stream) {
  const float* x   = (const float*)d_in[0];
  const int*   seq = (const int*)d_in[1];
  const float* emb = (const float*)d_in[2];
  const float* Wq  = (const float*)d_in[3];
  const float* bq  = (const float*)d_in[4];
  const float* Wk  = (const float*)d_in[5];
  const float* bk  = (const float*)d_in[6];
  const float* Wv  = (const float*)d_in[7];
  const float* bv  = (const float*)d_in[8];
  const float* W1  = (const float*)d_in[9];
  const float* b1  = (const float*)d_in[10];
  const float* W2  = (const float*)d_in[11];
  const float* b2  = (const float*)d_in[12];
  char* ws = (char*)d_ws;

  prep_kv<<<64, 512, 0, stream>>>(emb, seq, Wk, bk, Wv, bv, (float*)ws);
  prep_frag<<<209, 256, 0, stream>>>(Wq, bq, W1, ws);
  credit_main<<<512, 512, 0, stream>>>(x, ws, b1, W2, b2, (float*)d_out);
}